// Round 3
// baseline (822.757 us; speedup 1.0000x reference)
//
#include <hip/hip_runtime.h>
#include <cstddef>

#define B_  16384
#define F_  2048
#define T_  64
#define C_  32
#define H_  24
#define HH_ 48
#define RPT 8                    // rows per thread (register-blocked)
#define THR 256                  // threads per block
#define ROWS_BLK (RPT * THR)     // 2048 rows per block
#define NCHUNK (B_ / ROWS_BLK)   // 8 row-chunks per t

// ---------------------------------------------------------------------------
// Kernel A: block = (t, chunk of 2048 rows). Each thread register-blocks 8
// rows: s[8][24] = x-tile @ W accumulated with W read ONCE per wave per c
// (LDS broadcast, amortized 8x). x is consumed single-pass via the identity
//   err = sum_c (y_c + w2_c)^2 - 2(|s|^2 + hb.s) + sum_c x_c^2 - 2 sum vb_c x_c
// with y = W s, w2 = W hb + vb. No atomics: one partial per block.
// ---------------------------------------------------------------------------
__global__ __launch_bounds__(THR, 2) void kitnet_main(
    const float* __restrict__ x, const int* __restrict__ clusters,
    const float* __restrict__ Wt, const float* __restrict__ hb,
    const float* __restrict__ vb, float* __restrict__ partial)
{
    __shared__ __align__(16) float WL[C_ * H_];   // W[c][j], 24-float rows (96 B, 16B-aligned)
    __shared__ __align__(16) float hbL[H_];
    __shared__ __align__(16) float vbL[C_];
    __shared__ __align__(16) float w2L[C_];       // (W hb + vb)_c
    __shared__ int   colsL[C_];
    __shared__ int   contigS;
    __shared__ float wsum[4];

    const int tid   = threadIdx.x;
    const int t     = blockIdx.x & (T_ - 1);
    const int chunk = blockIdx.x >> 6;
    const int b0    = chunk * ROWS_BLK;

    // ---- stage per-t params ----
    for (int i = tid; i < C_ * H_; i += THR) WL[i] = Wt[t * C_ * H_ + i];
    if (tid < C_) { vbL[tid] = vb[t * C_ + tid]; colsL[tid] = clusters[t * C_ + tid]; }
    if (tid < H_) hbL[tid] = hb[t * H_ + tid];
    __syncthreads();

    if (tid < C_) {
        float acc = vbL[tid];
        #pragma unroll
        for (int j = 0; j < H_; ++j) acc += WL[tid * H_ + j] * hbL[j];
        w2L[tid] = acc;
    }
    if (tid == 0) {
        int ok = (colsL[0] & 3) == 0;
        for (int c = 1; c < C_; ++c) ok &= (colsL[c] == colsL[0] + c);
        contigS = ok;
    }
    __syncthreads();
    const int contig = contigS;
    const int col0   = colsL[0];

    float s[RPT][H_];
    #pragma unroll
    for (int r = 0; r < RPT; ++r)
        #pragma unroll
        for (int j = 0; j < H_; ++j) s[r][j] = 0.f;

    float err = 0.f;
    const size_t rowbase = (size_t)(b0 + tid) * F_;

    // ---- pass 1: s = x @ W, plus x-stats, c4-tiled so x streams through regs ----
    if (contig) {
        for (int c4 = 0; c4 < C_ / 4; ++c4) {
            float4 xq[RPT];
            #pragma unroll
            for (int r = 0; r < RPT; ++r)
                xq[r] = *(const float4*)(x + rowbase + (size_t)r * (THR * F_) + col0 + c4 * 4);
            #pragma unroll
            for (int cc = 0; cc < 4; ++cc) {
                const int c = c4 * 4 + cc;
                const float vbc = vbL[c];
                #pragma unroll
                for (int j4 = 0; j4 < H_ / 4; ++j4) {
                    const float4 w = *(const float4*)&WL[c * H_ + j4 * 4];
                    #pragma unroll
                    for (int r = 0; r < RPT; ++r) {
                        const float xc = (&xq[r].x)[cc];
                        s[r][j4 * 4 + 0] += xc * w.x;
                        s[r][j4 * 4 + 1] += xc * w.y;
                        s[r][j4 * 4 + 2] += xc * w.z;
                        s[r][j4 * 4 + 3] += xc * w.w;
                    }
                }
                #pragma unroll
                for (int r = 0; r < RPT; ++r) {
                    const float xc = (&xq[r].x)[cc];
                    err += xc * xc;
                    err -= 2.f * vbc * xc;
                }
            }
        }
    } else {
        for (int c4 = 0; c4 < C_ / 4; ++c4) {
            float4 xq[RPT];
            #pragma unroll
            for (int r = 0; r < RPT; ++r) {
                (&xq[r].x)[0] = x[rowbase + (size_t)r * (THR * F_) + colsL[c4 * 4 + 0]];
                (&xq[r].x)[1] = x[rowbase + (size_t)r * (THR * F_) + colsL[c4 * 4 + 1]];
                (&xq[r].x)[2] = x[rowbase + (size_t)r * (THR * F_) + colsL[c4 * 4 + 2]];
                (&xq[r].x)[3] = x[rowbase + (size_t)r * (THR * F_) + colsL[c4 * 4 + 3]];
            }
            #pragma unroll
            for (int cc = 0; cc < 4; ++cc) {
                const int c = c4 * 4 + cc;
                const float vbc = vbL[c];
                #pragma unroll
                for (int j4 = 0; j4 < H_ / 4; ++j4) {
                    const float4 w = *(const float4*)&WL[c * H_ + j4 * 4];
                    #pragma unroll
                    for (int r = 0; r < RPT; ++r) {
                        const float xc = (&xq[r].x)[cc];
                        s[r][j4 * 4 + 0] += xc * w.x;
                        s[r][j4 * 4 + 1] += xc * w.y;
                        s[r][j4 * 4 + 2] += xc * w.z;
                        s[r][j4 * 4 + 3] += xc * w.w;
                    }
                }
                #pragma unroll
                for (int r = 0; r < RPT; ++r) {
                    const float xc = (&xq[r].x)[cc];
                    err += xc * xc;
                    err -= 2.f * vbc * xc;
                }
            }
        }
    }

    // ---- pass 2: y = W s (c rolled, j4/r unrolled), err += (y + w2_c)^2 ----
    for (int c = 0; c < C_; ++c) {
        float y[RPT];
        #pragma unroll
        for (int r = 0; r < RPT; ++r) y[r] = 0.f;
        #pragma unroll
        for (int j4 = 0; j4 < H_ / 4; ++j4) {
            const float4 w = *(const float4*)&WL[c * H_ + j4 * 4];
            #pragma unroll
            for (int r = 0; r < RPT; ++r) {
                y[r] += w.x * s[r][j4 * 4 + 0] + w.y * s[r][j4 * 4 + 1]
                      + w.z * s[r][j4 * 4 + 2] + w.w * s[r][j4 * 4 + 3];
            }
        }
        const float w2c = w2L[c];
        #pragma unroll
        for (int r = 0; r < RPT; ++r) {
            const float o = y[r] + w2c;
            err += o * o;
        }
    }

    // ---- err -= 2*(|s|^2 + hb.s) ----
    #pragma unroll
    for (int j4 = 0; j4 < H_ / 4; ++j4) {
        const float4 h4 = *(const float4*)&hbL[j4 * 4];
        #pragma unroll
        for (int r = 0; r < RPT; ++r) {
            err -= 2.f * (s[r][j4 * 4 + 0] + h4.x) * s[r][j4 * 4 + 0];
            err -= 2.f * (s[r][j4 * 4 + 1] + h4.y) * s[r][j4 * 4 + 1];
            err -= 2.f * (s[r][j4 * 4 + 2] + h4.z) * s[r][j4 * 4 + 2];
            err -= 2.f * (s[r][j4 * 4 + 3] + h4.w) * s[r][j4 * 4 + 3];
        }
    }

    // ---- reduce: wave shuffle -> block -> one partial per block (no atomics) ----
    #pragma unroll
    for (int off = 32; off > 0; off >>= 1) err += __shfl_down(err, off, 64);
    if ((tid & 63) == 0) wsum[tid >> 6] = err;
    __syncthreads();
    if (tid == 0) partial[blockIdx.x] = wsum[0] + wsum[1] + wsum[2] + wsum[3];
}

// ---------------------------------------------------------------------------
// Kernel B: sum partials -> tails -> 2 tiny head matmuls. One wave.
// d_out = [ head_out (64) | tails (64) ]
// ---------------------------------------------------------------------------
__global__ __launch_bounds__(64) void kitnet_head(
    const float* __restrict__ partial, const float* __restrict__ Wh,
    const float* __restrict__ hbh, const float* __restrict__ vbh,
    float* __restrict__ out)
{
    __shared__ float tl[T_];
    __shared__ float hhL[HH_];
    const int tid = threadIdx.x;

    float sse = 0.f;
    #pragma unroll
    for (int c = 0; c < NCHUNK; ++c) sse += partial[c * T_ + tid];

    // tails[t] = log(sqrt(mean)) = 0.5*log(sse/(B*C))
    const float tail = 0.5f * logf(sse * (1.0f / ((float)B_ * (float)C_)));
    tl[tid] = tail;
    out[T_ + tid] = tail;
    __syncthreads();

    if (tid < HH_) {
        float acc = hbh[tid];
        #pragma unroll 8
        for (int t = 0; t < T_; ++t) acc += tl[t] * Wh[t * HH_ + tid];
        hhL[tid] = acc;
    }
    __syncthreads();

    float ho = vbh[tid];
    #pragma unroll 8
    for (int j = 0; j < HH_; ++j) ho += hhL[j] * Wh[tid * HH_ + j];
    out[tid] = ho;
}

extern "C" void kernel_launch(void* const* d_in, const int* in_sizes, int n_in,
                              void* d_out, int out_size, void* d_ws, size_t ws_size,
                              hipStream_t stream)
{
    const float* x        = (const float*)d_in[0];
    const int*   clusters = (const int*)  d_in[1];
    const float* Wt       = (const float*)d_in[2];
    const float* hb       = (const float*)d_in[3];
    const float* vb       = (const float*)d_in[4];
    const float* Wh       = (const float*)d_in[5];
    const float* hbh      = (const float*)d_in[6];
    const float* vbh      = (const float*)d_in[7];
    float* out     = (float*)d_out;
    float* partial = (float*)d_ws;   // NCHUNK*T_ floats; every slot written each call

    kitnet_main<<<dim3(T_ * NCHUNK), dim3(THR), 0, stream>>>(x, clusters, Wt, hb, vb, partial);
    kitnet_head<<<dim3(1), dim3(64), 0, stream>>>(partial, Wh, hbh, vbh, out);
}

// Round 4
// 322.778 us; speedup vs baseline: 2.5490x; 2.5490x over previous
//
#include <hip/hip_runtime.h>
#include <cstddef>

#define B_  16384
#define F_  2048
#define T_  64
#define C_  32
#define H_  24
#define HH_ 48
#define RPT 4                    // rows per thread (s[4][24]=96 VGPR, fits)
#define THR 256                  // threads per block
#define ROWS_BLK (RPT * THR)     // 1024 rows per block
#define NCHUNK (B_ / ROWS_BLK)   // 16 row-chunks per t

// ---------------------------------------------------------------------------
// err_row = s^T (G-2I) s + d.s + k0 + sum_c x_c (x_c - 2 w2_c)
//   s  = x . W            (per-row hidden pre-bias)
//   G  = W^T W            (24x24, per-block precompute)
//   w2 = W hb + vb        (C)
//   d  = 2 (W^T w2 - hb)  (H)
//   k0 = |w2|^2           (scalar)
// x is consumed streaming in pass 1; pass 2 is a 24x24 quadratic form from
// LDS-broadcast G. W/G read once per thread, amortized over RPT rows.
// ---------------------------------------------------------------------------
__global__ __launch_bounds__(THR) void kitnet_main(
    const float* __restrict__ x, const int* __restrict__ clusters,
    const float* __restrict__ Wt, const float* __restrict__ hb,
    const float* __restrict__ vb, float* __restrict__ partial)
{
    __shared__ __align__(16) float WL[C_ * H_];   // W[c][j]
    __shared__ __align__(16) float GL[H_ * H_];   // G' = W^T W - 2I
    __shared__ __align__(16) float w2L[C_];
    __shared__ __align__(16) float dL[H_];
    __shared__ __align__(16) float hbL[H_];
    __shared__ float k0L;
    __shared__ int   colsL[C_];
    __shared__ int   contigS;
    __shared__ float wsum[4];

    const int tid   = threadIdx.x;
    const int t     = blockIdx.x & (T_ - 1);
    const int chunk = blockIdx.x >> 6;
    const int b0    = chunk * ROWS_BLK;

    // ---- phase 1: stage W, hb, cols ----
    for (int i = tid; i < C_ * H_; i += THR) WL[i] = Wt[t * C_ * H_ + i];
    if (tid < H_) hbL[tid] = hb[t * H_ + tid];
    if (tid < C_) colsL[tid] = clusters[t * C_ + tid];
    __syncthreads();

    // ---- phase 2: w2, contiguity ----
    if (tid < C_) {
        float a = vb[t * C_ + tid];
        #pragma unroll
        for (int j = 0; j < H_; ++j) a += WL[tid * H_ + j] * hbL[j];
        w2L[tid] = a;
    }
    if (tid == 0) {
        int ok = (colsL[0] & 3) == 0;
        for (int c = 1; c < C_; ++c) ok &= (colsL[c] == colsL[0] + c);
        contigS = ok;
    }
    __syncthreads();

    // ---- phase 3: G', d, k0 ----
    for (int idx = tid; idx < H_ * H_; idx += THR) {
        const int i = idx / H_, j = idx - i * H_;
        float a = 0.f;
        #pragma unroll
        for (int c = 0; c < C_; ++c) a += WL[c * H_ + i] * WL[c * H_ + j];
        GL[idx] = (i == j) ? a - 2.f : a;
    }
    if (tid < H_) {
        float a = 0.f;
        #pragma unroll
        for (int c = 0; c < C_; ++c) a += w2L[c] * WL[c * H_ + tid];
        dL[tid] = 2.f * (a - hbL[tid]);
    }
    if (tid == THR - 1) {
        float a = 0.f;
        for (int c = 0; c < C_; ++c) a += w2L[c] * w2L[c];
        k0L = a;
    }
    __syncthreads();

    const int contig = contigS;
    const int col0   = colsL[0];

    float s[RPT][H_];
    #pragma unroll
    for (int r = 0; r < RPT; ++r)
        #pragma unroll
        for (int j = 0; j < H_; ++j) s[r][j] = 0.f;

    float err = 0.f;
    const float* xrow = x + (size_t)(b0 + tid) * F_;   // rows: +r*THR

    // ---- pass 1: s = x.W, err += x(x-2*w2) ----
    if (contig) {
        for (int c4 = 0; c4 < C_ / 4; ++c4) {
            float4 xq[RPT];
            #pragma unroll
            for (int r = 0; r < RPT; ++r)
                xq[r] = *(const float4*)(xrow + (size_t)r * (THR * (size_t)F_) + col0 + c4 * 4);
#define CCBODY(cc, comp)                                                      \
            {                                                                 \
                const int c = c4 * 4 + cc;                                    \
                const float w2c = w2L[c];                                     \
                _Pragma("unroll")                                             \
                for (int j4 = 0; j4 < H_ / 4; ++j4) {                         \
                    const float4 w = *(const float4*)&WL[c * H_ + j4 * 4];    \
                    _Pragma("unroll")                                         \
                    for (int r = 0; r < RPT; ++r) {                           \
                        s[r][j4 * 4 + 0] += xq[r].comp * w.x;                 \
                        s[r][j4 * 4 + 1] += xq[r].comp * w.y;                 \
                        s[r][j4 * 4 + 2] += xq[r].comp * w.z;                 \
                        s[r][j4 * 4 + 3] += xq[r].comp * w.w;                 \
                    }                                                         \
                }                                                             \
                _Pragma("unroll")                                             \
                for (int r = 0; r < RPT; ++r)                                 \
                    err += xq[r].comp * (xq[r].comp - 2.f * w2c);             \
            }
            CCBODY(0, x) CCBODY(1, y) CCBODY(2, z) CCBODY(3, w)
#undef CCBODY
        }
    } else {
        for (int c = 0; c < C_; ++c) {
            const int  cl  = colsL[c];
            const float w2c = w2L[c];
            float xc[RPT];
            #pragma unroll
            for (int r = 0; r < RPT; ++r)
                xc[r] = xrow[(size_t)r * (THR * (size_t)F_) + cl];
            #pragma unroll
            for (int j4 = 0; j4 < H_ / 4; ++j4) {
                const float4 w = *(const float4*)&WL[c * H_ + j4 * 4];
                #pragma unroll
                for (int r = 0; r < RPT; ++r) {
                    s[r][j4 * 4 + 0] += xc[r] * w.x;
                    s[r][j4 * 4 + 1] += xc[r] * w.y;
                    s[r][j4 * 4 + 2] += xc[r] * w.z;
                    s[r][j4 * 4 + 3] += xc[r] * w.w;
                }
            }
            #pragma unroll
            for (int r = 0; r < RPT; ++r)
                err += xc[r] * (xc[r] - 2.f * w2c);
        }
    }

    // ---- pass 2: err += s^T G' s + d.s   (j fully unrolled: s[] stays in VGPRs)
    #pragma unroll
    for (int j = 0; j < H_; ++j) {
        float q[RPT];
        #pragma unroll
        for (int r = 0; r < RPT; ++r) q[r] = 0.f;
        #pragma unroll
        for (int i4 = 0; i4 < H_ / 4; ++i4) {
            const float4 g = *(const float4*)&GL[j * H_ + i4 * 4];
            #pragma unroll
            for (int r = 0; r < RPT; ++r)
                q[r] += g.x * s[r][i4 * 4 + 0] + g.y * s[r][i4 * 4 + 1]
                      + g.z * s[r][i4 * 4 + 2] + g.w * s[r][i4 * 4 + 3];
        }
        const float dj = dL[j];
        #pragma unroll
        for (int r = 0; r < RPT; ++r) err += (q[r] + dj) * s[r][j];
    }
    err += (float)RPT * k0L;

    // ---- reduce: wave shuffle -> block -> one partial per block ----
    #pragma unroll
    for (int off = 32; off > 0; off >>= 1) err += __shfl_down(err, off, 64);
    if ((tid & 63) == 0) wsum[tid >> 6] = err;
    __syncthreads();
    if (tid == 0) partial[blockIdx.x] = wsum[0] + wsum[1] + wsum[2] + wsum[3];
}

// ---------------------------------------------------------------------------
// Kernel B: sum partials -> tails -> 2 tiny head matmuls. One wave.
// d_out = [ head_out (64) | tails (64) ]
// ---------------------------------------------------------------------------
__global__ __launch_bounds__(64) void kitnet_head(
    const float* __restrict__ partial, const float* __restrict__ Wh,
    const float* __restrict__ hbh, const float* __restrict__ vbh,
    float* __restrict__ out)
{
    __shared__ float tl[T_];
    __shared__ float hhL[HH_];
    const int tid = threadIdx.x;

    float sse = 0.f;
    #pragma unroll
    for (int c = 0; c < NCHUNK; ++c) sse += partial[c * T_ + tid];

    const float tail = 0.5f * logf(sse * (1.0f / ((float)B_ * (float)C_)));
    tl[tid] = tail;
    out[T_ + tid] = tail;
    __syncthreads();

    if (tid < HH_) {
        float acc = hbh[tid];
        #pragma unroll 8
        for (int t = 0; t < T_; ++t) acc += tl[t] * Wh[t * HH_ + tid];
        hhL[tid] = acc;
    }
    __syncthreads();

    float ho = vbh[tid];
    #pragma unroll 8
    for (int j = 0; j < HH_; ++j) ho += hhL[j] * Wh[tid * HH_ + j];
    out[tid] = ho;
}

extern "C" void kernel_launch(void* const* d_in, const int* in_sizes, int n_in,
                              void* d_out, int out_size, void* d_ws, size_t ws_size,
                              hipStream_t stream)
{
    const float* x        = (const float*)d_in[0];
    const int*   clusters = (const int*)  d_in[1];
    const float* Wt       = (const float*)d_in[2];
    const float* hb       = (const float*)d_in[3];
    const float* vb       = (const float*)d_in[4];
    const float* Wh       = (const float*)d_in[5];
    const float* hbh      = (const float*)d_in[6];
    const float* vbh      = (const float*)d_in[7];
    float* out     = (float*)d_out;
    float* partial = (float*)d_ws;   // NCHUNK*T_ floats; every slot written each call

    kitnet_main<<<dim3(T_ * NCHUNK), dim3(THR), 0, stream>>>(x, clusters, Wt, hb, vb, partial);
    kitnet_head<<<dim3(1), dim3(64), 0, stream>>>(partial, Wh, hbh, vbh, out);
}

// Round 5
// 264.620 us; speedup vs baseline: 3.1092x; 1.2198x over previous
//
#include <hip/hip_runtime.h>
#include <cstddef>

#define B_  16384
#define F_  2048
#define T_  64
#define C_  32
#define H_  24
#define HH_ 48
#define RPT 4                    // rows per thread
#define THR 256                  // threads per block
#define ROWS_BLK (RPT * THR)     // 1024 rows per block
#define NCHUNK (B_ / ROWS_BLK)   // 16 row-chunks per t

// ---------------------------------------------------------------------------
// err_row = s^T (G-2I) s + d.s + k0 + sum_c x_c (x_c - 2 w2_c)
//   s = x.W ; G = W^T W ; w2 = W hb + vb ; d = 2(W^T w2 - hb) ; k0 = |w2|^2
// Pass 1 loads each row's FULL 128-B gathered segment up-front into registers
// (8 same-line dwordx4 -> one HBM fetch per line, consumed once), then the
// W-amortized c4-outer FMA sweep runs entirely from registers + LDS broadcast.
// ---------------------------------------------------------------------------
__global__ __launch_bounds__(THR) void kitnet_main(
    const float* __restrict__ x, const int* __restrict__ clusters,
    const float* __restrict__ Wt, const float* __restrict__ hb,
    const float* __restrict__ vb, float* __restrict__ partial)
{
    __shared__ __align__(16) float WL[C_ * H_];   // W[c][j]
    __shared__ __align__(16) float GL[H_ * H_];   // G' = W^T W - 2I
    __shared__ __align__(16) float w2L[C_];
    __shared__ __align__(16) float dL[H_];
    __shared__ __align__(16) float hbL[H_];
    __shared__ float k0L;
    __shared__ int   colsL[C_];
    __shared__ int   contigS;
    __shared__ float wsum[4];

    const int tid   = threadIdx.x;
    const int t     = blockIdx.x & (T_ - 1);
    const int chunk = blockIdx.x >> 6;
    const int b0    = chunk * ROWS_BLK;

    // ---- phase 1: stage W, hb, cols ----
    for (int i = tid; i < C_ * H_; i += THR) WL[i] = Wt[t * C_ * H_ + i];
    if (tid < H_) hbL[tid] = hb[t * H_ + tid];
    if (tid < C_) colsL[tid] = clusters[t * C_ + tid];
    __syncthreads();

    // ---- phase 2: w2, contiguity ----
    if (tid < C_) {
        float a = vb[t * C_ + tid];
        #pragma unroll
        for (int j = 0; j < H_; ++j) a += WL[tid * H_ + j] * hbL[j];
        w2L[tid] = a;
    }
    if (tid == 0) {
        int ok = (colsL[0] & 3) == 0;
        for (int c = 1; c < C_; ++c) ok &= (colsL[c] == colsL[0] + c);
        contigS = ok;
    }
    __syncthreads();

    // ---- phase 3: G', d, k0 ----
    for (int idx = tid; idx < H_ * H_; idx += THR) {
        const int i = idx / H_, j = idx - i * H_;
        float a = 0.f;
        #pragma unroll
        for (int c = 0; c < C_; ++c) a += WL[c * H_ + i] * WL[c * H_ + j];
        GL[idx] = (i == j) ? a - 2.f : a;
    }
    if (tid < H_) {
        float a = 0.f;
        #pragma unroll
        for (int c = 0; c < C_; ++c) a += w2L[c] * WL[c * H_ + tid];
        dL[tid] = 2.f * (a - hbL[tid]);
    }
    if (tid == THR - 1) {
        float a = 0.f;
        for (int c = 0; c < C_; ++c) a += w2L[c] * w2L[c];
        k0L = a;
    }
    __syncthreads();

    const int contig = contigS;
    const int col0   = colsL[0];

    float s[RPT][H_];
    #pragma unroll
    for (int r = 0; r < RPT; ++r)
        #pragma unroll
        for (int j = 0; j < H_; ++j) s[r][j] = 0.f;

    float err = 0.f;
    const float* xrow = x + (size_t)(b0 + tid) * F_;   // rows: +r*THR

    if (contig) {
        // ---- load all 4 rows' full 128-B segments up-front (line-ordered) ----
        float4 xq[RPT][8];
        #pragma unroll
        for (int r = 0; r < RPT; ++r) {
            const float* rp = xrow + (size_t)r * (THR * (size_t)F_) + col0;
            #pragma unroll
            for (int k = 0; k < 8; ++k)
                xq[r][k] = *(const float4*)(rp + k * 4);
        }
        // ---- pass 1: s = x.W, err += x(x-2*w2), W read once per c (x4 reuse)
        #pragma unroll
        for (int c4 = 0; c4 < 8; ++c4) {
#define CCBODY(cc, comp)                                                      \
            {                                                                 \
                const int c = c4 * 4 + cc;                                    \
                const float w2c = w2L[c];                                     \
                _Pragma("unroll")                                             \
                for (int j4 = 0; j4 < H_ / 4; ++j4) {                         \
                    const float4 w = *(const float4*)&WL[c * H_ + j4 * 4];    \
                    _Pragma("unroll")                                         \
                    for (int r = 0; r < RPT; ++r) {                           \
                        s[r][j4 * 4 + 0] += xq[r][c4].comp * w.x;             \
                        s[r][j4 * 4 + 1] += xq[r][c4].comp * w.y;             \
                        s[r][j4 * 4 + 2] += xq[r][c4].comp * w.z;             \
                        s[r][j4 * 4 + 3] += xq[r][c4].comp * w.w;             \
                    }                                                         \
                }                                                             \
                _Pragma("unroll")                                             \
                for (int r = 0; r < RPT; ++r)                                 \
                    err += xq[r][c4].comp * (xq[r][c4].comp - 2.f * w2c);     \
            }
            CCBODY(0, x) CCBODY(1, y) CCBODY(2, z) CCBODY(3, w)
#undef CCBODY
        }
    } else {
        for (int c = 0; c < C_; ++c) {
            const int  cl  = colsL[c];
            const float w2c = w2L[c];
            float xc[RPT];
            #pragma unroll
            for (int r = 0; r < RPT; ++r)
                xc[r] = xrow[(size_t)r * (THR * (size_t)F_) + cl];
            #pragma unroll
            for (int j4 = 0; j4 < H_ / 4; ++j4) {
                const float4 w = *(const float4*)&WL[c * H_ + j4 * 4];
                #pragma unroll
                for (int r = 0; r < RPT; ++r) {
                    s[r][j4 * 4 + 0] += xc[r] * w.x;
                    s[r][j4 * 4 + 1] += xc[r] * w.y;
                    s[r][j4 * 4 + 2] += xc[r] * w.z;
                    s[r][j4 * 4 + 3] += xc[r] * w.w;
                }
            }
            #pragma unroll
            for (int r = 0; r < RPT; ++r)
                err += xc[r] * (xc[r] - 2.f * w2c);
        }
    }

    // ---- pass 2: err += s^T G' s + d.s  (fully unrolled: s stays in regs)
    #pragma unroll
    for (int j = 0; j < H_; ++j) {
        float q[RPT];
        #pragma unroll
        for (int r = 0; r < RPT; ++r) q[r] = 0.f;
        #pragma unroll
        for (int i4 = 0; i4 < H_ / 4; ++i4) {
            const float4 g = *(const float4*)&GL[j * H_ + i4 * 4];
            #pragma unroll
            for (int r = 0; r < RPT; ++r)
                q[r] += g.x * s[r][i4 * 4 + 0] + g.y * s[r][i4 * 4 + 1]
                      + g.z * s[r][i4 * 4 + 2] + g.w * s[r][i4 * 4 + 3];
        }
        const float dj = dL[j];
        #pragma unroll
        for (int r = 0; r < RPT; ++r) err += (q[r] + dj) * s[r][j];
    }
    err += (float)RPT * k0L;

    // ---- reduce: wave shuffle -> block -> one partial per block ----
    #pragma unroll
    for (int off = 32; off > 0; off >>= 1) err += __shfl_down(err, off, 64);
    if ((tid & 63) == 0) wsum[tid >> 6] = err;
    __syncthreads();
    if (tid == 0) partial[blockIdx.x] = wsum[0] + wsum[1] + wsum[2] + wsum[3];
}

// ---------------------------------------------------------------------------
// Kernel B: sum partials -> tails -> 2 tiny head matmuls. One wave.
// d_out = [ head_out (64) | tails (64) ]
// ---------------------------------------------------------------------------
__global__ __launch_bounds__(64) void kitnet_head(
    const float* __restrict__ partial, const float* __restrict__ Wh,
    const float* __restrict__ hbh, const float* __restrict__ vbh,
    float* __restrict__ out)
{
    __shared__ float tl[T_];
    __shared__ float hhL[HH_];
    const int tid = threadIdx.x;

    float sse = 0.f;
    #pragma unroll
    for (int c = 0; c < NCHUNK; ++c) sse += partial[c * T_ + tid];

    const float tail = 0.5f * logf(sse * (1.0f / ((float)B_ * (float)C_)));
    tl[tid] = tail;
    out[T_ + tid] = tail;
    __syncthreads();

    if (tid < HH_) {
        float acc = hbh[tid];
        #pragma unroll 8
        for (int t = 0; t < T_; ++t) acc += tl[t] * Wh[t * HH_ + tid];
        hhL[tid] = acc;
    }
    __syncthreads();

    float ho = vbh[tid];
    #pragma unroll 8
    for (int j = 0; j < HH_; ++j) ho += hhL[j] * Wh[tid * HH_ + j];
    out[tid] = ho;
}

extern "C" void kernel_launch(void* const* d_in, const int* in_sizes, int n_in,
                              void* d_out, int out_size, void* d_ws, size_t ws_size,
                              hipStream_t stream)
{
    const float* x        = (const float*)d_in[0];
    const int*   clusters = (const int*)  d_in[1];
    const float* Wt       = (const float*)d_in[2];
    const float* hb       = (const float*)d_in[3];
    const float* vb       = (const float*)d_in[4];
    const float* Wh       = (const float*)d_in[5];
    const float* hbh      = (const float*)d_in[6];
    const float* vbh      = (const float*)d_in[7];
    float* out     = (float*)d_out;
    float* partial = (float*)d_ws;   // NCHUNK*T_ floats; every slot written each call

    kitnet_main<<<dim3(T_ * NCHUNK), dim3(THR), 0, stream>>>(x, clusters, Wt, hb, vb, partial);
    kitnet_head<<<dim3(1), dim3(64), 0, stream>>>(partial, Wh, hbh, vbh, out);
}

// Round 6
// 217.697 us; speedup vs baseline: 3.7794x; 1.2155x over previous
//
#include <hip/hip_runtime.h>
#include <cstddef>

#define B_  16384
#define F_  2048
#define T_  64
#define C_  32
#define H_  24
#define HH_ 48
#define THR 256
#define ROWS_BLK 1024
#define NCHUNK (B_ / ROWS_BLK)   // 16
#define SL_STRIDE 72             // shorts per S_lds row (144 B: 16B-aligned, 2-way banks)

typedef __attribute__((ext_vector_type(8))) short  short8;   // 8 bf16 (4 VGPRs)
typedef __attribute__((ext_vector_type(4))) float  floatx4;

__device__ __forceinline__ short f2bf(float f) {   // fp32 -> bf16 bits, RNE
    union { float f; unsigned u; } v; v.f = f;
    unsigned r = v.u + 0x7FFFu + ((v.u >> 16) & 1u);
    return (short)(r >> 16);
}

// ---------------------------------------------------------------------------
// err_row = s^T (G-2I) s + d.s + k0 + sum_c x_c (x_c - 2 w2_c)   (R4 identity)
// Both GEMMs (S = X.W 16x32x24 and Q = S.G' 16x32(pad)x24) via
// mfma_f32_16x16x32_bf16. W/G'/w2/d live in per-wave reg fragments; the D->A
// layout hop for the 2nd MFMA round-trips a per-wave LDS tile (m120 pattern).
// xstats stay fp32. Per-wave: 16 groups of 16 rows, one-ahead prefetch.
// ---------------------------------------------------------------------------
__global__ __launch_bounds__(THR) void kitnet_main(
    const float* __restrict__ x, const int* __restrict__ clusters,
    const float* __restrict__ Wt, const float* __restrict__ hb,
    const float* __restrict__ vb, float* __restrict__ partial)
{
    __shared__ __align__(16) float WL[C_ * H_];   // W[c][j]
    __shared__ __align__(16) float GL[H_ * H_];   // G' = W^T W - 2I
    __shared__ __align__(16) float w2L[C_];
    __shared__ __align__(16) float dL[H_];
    __shared__ __align__(16) float hbL[H_];
    __shared__ float k0L;
    __shared__ int   colsL[C_];
    __shared__ int   contigS;
    __shared__ float wsum[4];
    __shared__ __align__(16) short Sl[4 * 16 * SL_STRIDE];  // per-wave S tiles

    const int tid   = threadIdx.x;
    const int t     = blockIdx.x >> 4;            // chunk-fastest: XCD = chunk%8
    const int chunk = blockIdx.x & (NCHUNK - 1);
    const int b0    = chunk * ROWS_BLK;

    // ---- phase 1: stage W, hb, cols ----
    for (int i = tid; i < C_ * H_; i += THR) WL[i] = Wt[t * C_ * H_ + i];
    if (tid < H_) hbL[tid] = hb[t * H_ + tid];
    if (tid < C_) colsL[tid] = clusters[t * C_ + tid];
    __syncthreads();

    // ---- phase 2: w2, contiguity ----
    if (tid < C_) {
        float a = vb[t * C_ + tid];
        #pragma unroll
        for (int j = 0; j < H_; ++j) a += WL[tid * H_ + j] * hbL[j];
        w2L[tid] = a;
    }
    if (tid == 0) {
        int ok = (colsL[0] & 3) == 0;
        for (int c = 1; c < C_; ++c) ok &= (colsL[c] == colsL[0] + c);
        contigS = ok;
    }
    __syncthreads();

    // ---- phase 3: G', d, k0 ----
    for (int idx = tid; idx < H_ * H_; idx += THR) {
        const int i = idx / H_, j = idx - i * H_;
        float a = 0.f;
        #pragma unroll
        for (int c = 0; c < C_; ++c) a += WL[c * H_ + i] * WL[c * H_ + j];
        GL[idx] = (i == j) ? a - 2.f : a;
    }
    if (tid < H_) {
        float a = 0.f;
        #pragma unroll
        for (int c = 0; c < C_; ++c) a += w2L[c] * WL[c * H_ + tid];
        dL[tid] = 2.f * (a - hbL[tid]);
    }
    if (tid == THR - 1) {
        float a = 0.f;
        for (int c = 0; c < C_; ++c) a += w2L[c] * w2L[c];
        k0L = a;
    }
    __syncthreads();

    const int lane = tid & 63;
    const int wid  = tid >> 6;
    const int m    = lane & 15;    // A row / B-D col
    const int quad = lane >> 4;    // k-slice

    // ---- per-wave constant fragments (built once, reused for 16 groups) ----
    short8 bw0, bw1, gg0, gg1;
    float  w2f[8];
    #pragma unroll
    for (int j = 0; j < 8; ++j) {
        const int k = quad * 8 + j;
        bw0[j] = f2bf(WL[k * H_ + m]);                                 // W[c][n]
        bw1[j] = (m < 8) ? f2bf(WL[k * H_ + 16 + m]) : (short)0;       // n=16..23
        gg0[j] = (k < H_) ? f2bf(GL[k * H_ + m]) : (short)0;           // G'[j][i]
        gg1[j] = (k < H_ && m < 8) ? f2bf(GL[k * H_ + 16 + m]) : (short)0;
        w2f[j] = w2L[k];
    }
    const float d0 = dL[m];
    const float d1 = (m < 8) ? dL[16 + m] : 0.f;

    short* sl = &Sl[wid * 16 * SL_STRIDE];
    const int contig = contigS;
    const int col0   = colsL[0];
    float err = 0.f;

#define PROCESS16(X0, X1, X2, X3, X4, X5, X6, X7)                             \
    {                                                                         \
        const float xv_[8] = {X0, X1, X2, X3, X4, X5, X6, X7};                \
        short8 af;                                                            \
        _Pragma("unroll")                                                     \
        for (int j = 0; j < 8; ++j) {                                         \
            err += xv_[j] * (xv_[j] - 2.f * w2f[j]);                          \
            af[j] = f2bf(xv_[j]);                                             \
        }                                                                     \
        const floatx4 z_ = {0.f, 0.f, 0.f, 0.f};                              \
        floatx4 S0 = __builtin_amdgcn_mfma_f32_16x16x32_bf16(af, bw0, z_, 0, 0, 0); \
        floatx4 S1 = __builtin_amdgcn_mfma_f32_16x16x32_bf16(af, bw1, z_, 0, 0, 0); \
        _Pragma("unroll")                                                     \
        for (int r = 0; r < 4; ++r) {                                         \
            sl[(quad * 4 + r) * SL_STRIDE + m]      = f2bf(S0[r]);            \
            sl[(quad * 4 + r) * SL_STRIDE + 16 + m] = f2bf(S1[r]);            \
        }                                                                     \
        short8 sf = *(const short8*)&sl[m * SL_STRIDE + quad * 8];            \
        floatx4 Q0 = __builtin_amdgcn_mfma_f32_16x16x32_bf16(sf, gg0, z_, 0, 0, 0); \
        floatx4 Q1 = __builtin_amdgcn_mfma_f32_16x16x32_bf16(sf, gg1, z_, 0, 0, 0); \
        _Pragma("unroll")                                                     \
        for (int r = 0; r < 4; ++r)                                           \
            err += (Q0[r] + d0) * S0[r] + (Q1[r] + d1) * S1[r];               \
    }

    if (contig) {
        // lane loads 32 B contiguous of its row: full 128-B line per 4 lanes
        const float* xbase = x + (size_t)(b0 + wid * 256 + m) * F_ + col0 + quad * 8;
        float4 pa = *(const float4*)xbase;
        float4 pb = *(const float4*)(xbase + 4);
        for (int g = 0; g < 16; ++g) {
            const float4 xa = pa, xb = pb;
            if (g < 15) {
                const float* nx = xbase + (size_t)(g + 1) * 16 * F_;
                pa = *(const float4*)nx;
                pb = *(const float4*)(nx + 4);
            }
            PROCESS16(xa.x, xa.y, xa.z, xa.w, xb.x, xb.y, xb.z, xb.w)
        }
    } else {
        for (int g = 0; g < 16; ++g) {
            const size_t rb = (size_t)(b0 + wid * 256 + g * 16 + m) * F_;
            float xf[8];
            #pragma unroll
            for (int j = 0; j < 8; ++j) xf[j] = x[rb + colsL[quad * 8 + j]];
            PROCESS16(xf[0], xf[1], xf[2], xf[3], xf[4], xf[5], xf[6], xf[7])
        }
    }
#undef PROCESS16

    // ---- reduce: wave shuffle -> block -> one partial per block ----
    #pragma unroll
    for (int off = 32; off > 0; off >>= 1) err += __shfl_down(err, off, 64);
    if (lane == 0) wsum[wid] = err;
    __syncthreads();
    if (tid == 0)
        partial[blockIdx.x] = wsum[0] + wsum[1] + wsum[2] + wsum[3]
                            + (float)ROWS_BLK * k0L;
}

// ---------------------------------------------------------------------------
// Kernel B: sum partials -> tails -> 2 tiny head matmuls. One wave.
// d_out = [ head_out (64) | tails (64) ]
// ---------------------------------------------------------------------------
__global__ __launch_bounds__(64) void kitnet_head(
    const float* __restrict__ partial, const float* __restrict__ Wh,
    const float* __restrict__ hbh, const float* __restrict__ vbh,
    float* __restrict__ out)
{
    __shared__ float tl[T_];
    __shared__ float hhL[HH_];
    const int tid = threadIdx.x;

    float sse = 0.f;
    #pragma unroll
    for (int c = 0; c < NCHUNK; ++c) sse += partial[tid * NCHUNK + c];

    const float tail = 0.5f * logf(sse * (1.0f / ((float)B_ * (float)C_)));
    tl[tid] = tail;
    out[T_ + tid] = tail;
    __syncthreads();

    if (tid < HH_) {
        float acc = hbh[tid];
        #pragma unroll 8
        for (int t = 0; t < T_; ++t) acc += tl[t] * Wh[t * HH_ + tid];
        hhL[tid] = acc;
    }
    __syncthreads();

    float ho = vbh[tid];
    #pragma unroll 8
    for (int j = 0; j < HH_; ++j) ho += hhL[j] * Wh[tid * HH_ + j];
    out[tid] = ho;
}

extern "C" void kernel_launch(void* const* d_in, const int* in_sizes, int n_in,
                              void* d_out, int out_size, void* d_ws, size_t ws_size,
                              hipStream_t stream)
{
    const float* x        = (const float*)d_in[0];
    const int*   clusters = (const int*)  d_in[1];
    const float* Wt       = (const float*)d_in[2];
    const float* hb       = (const float*)d_in[3];
    const float* vb       = (const float*)d_in[4];
    const float* Wh       = (const float*)d_in[5];
    const float* hbh      = (const float*)d_in[6];
    const float* vbh      = (const float*)d_in[7];
    float* out     = (float*)d_out;
    float* partial = (float*)d_ws;   // T_*NCHUNK floats; every slot written each call

    kitnet_main<<<dim3(T_ * NCHUNK), dim3(THR), 0, stream>>>(x, clusters, Wt, hb, vb, partial);
    kitnet_head<<<dim3(1), dim3(64), 0, stream>>>(partial, Wh, hbh, vbh, out);
}